// Round 2
// baseline (751.221 us; speedup 1.0000x reference)
//
#include <hip/hip_runtime.h>
#include <stdint.h>

// ExpertRouter: logits = hidden @ W^T + b + routing_bias; softmax; top-2; renorm.
// hidden [4,4096,4096] f32, routing_bias [4,64] f32, W [64,4096] f32, b [64] f32
// out: 32768 f32 weights [B,S,2] ++ 32768 f32 indices [B,S,2]
//
// Design (R2): lanes = tokens, waves = expert groups. W is wave-uniform ->
// scalar (SGPR) loads, consumed as the SGPR operand of v_fmac_f32. Hidden
// staged to LDS as [k/4][token] float4 via global_load_lds (lane-contiguous,
// conflict-free ds_read_b128). One b128 per 32 FMAs per wave -> LDS pipe at
// ~62%, VALU becomes the limiter (fp32 FMA floor = 55 us).

#define D     4096
#define NE    64
#define TPB   64            // tokens per block (= lanes per wave)
#define KC    64            // k-chunk (floats per row per stage)
#define NCH   (D / KC)      // 64 chunks
#define NWAVE 8
#define EPW   (NE / NWAVE)  // 8 experts per wave

typedef const __attribute__((address_space(1))) unsigned int* gp_t;
typedef __attribute__((address_space(3))) unsigned int* lp_t;

__global__ __launch_bounds__(512)
void router_kernel(const float* __restrict__ hidden,
                   const float* __restrict__ rbias,
                   const float* __restrict__ W,
                   const float* __restrict__ bias,
                   float* __restrict__ out)
{
    __shared__ __align__(16) float4 Hs[2][KC / 4][TPB]; // 32 KB, [buf][kq][token]
    __shared__ float Ls[NE][TPB];                       // 16 KB logits

    const int tid   = threadIdx.x;
    const int lane  = tid & 63;
    const int w     = __builtin_amdgcn_readfirstlane(tid >> 6); // wave id, SGPR
    const int gt0   = blockIdx.x * TPB;
    const int batch = gt0 >> 12;          // 4096 tokens per batch, TPB | 4096

    const float* hrow = hidden + (size_t)(gt0 + lane) * D;      // per-lane token row
    const float* wb   = W + (size_t)(w * EPW) * D;              // wave-uniform

    float acc[EPW] = {0.f, 0.f, 0.f, 0.f, 0.f, 0.f, 0.f, 0.f};

    // ---- stage chunk 0: wave w loads slabs 2w, 2w+1 (each = 64 tokens x 16B) ----
    __builtin_amdgcn_global_load_lds((gp_t)(const void*)(hrow + (2 * w) * 4),
                                     (lp_t)(void*)&Hs[0][2 * w][0], 16, 0, 0);
    __builtin_amdgcn_global_load_lds((gp_t)(const void*)(hrow + (2 * w + 1) * 4),
                                     (lp_t)(void*)&Hs[0][2 * w + 1][0], 16, 0, 0);

    // ---- prefetch W quad k=0 (wave-uniform -> scalar loads) ----
    float4 wc[EPW], wn[EPW];
    #pragma unroll
    for (int j = 0; j < EPW; ++j) wc[j] = *(const float4*)(wb + (size_t)j * D);

    __syncthreads();

    for (int c = 0; c < NCH; ++c) {
        const int buf = c & 1;
        if (c + 1 < NCH) {  // stage next chunk into other buffer (in flight over compute)
            const float* src = hrow + (c + 1) * KC;
            __builtin_amdgcn_global_load_lds((gp_t)(const void*)(src + (2 * w) * 4),
                                             (lp_t)(void*)&Hs[buf ^ 1][2 * w][0], 16, 0, 0);
            __builtin_amdgcn_global_load_lds((gp_t)(const void*)(src + (2 * w + 1) * 4),
                                             (lp_t)(void*)&Hs[buf ^ 1][2 * w + 1][0], 16, 0, 0);
        }
        #pragma unroll
        for (int q = 0; q < KC / 4; ++q) {
            const int k  = c * KC + q * 4;
            const int kn = (k + 4 < D) ? (k + 4) : 0;   // clamp: avoid OOB prefetch
            #pragma unroll
            for (int j = 0; j < EPW; ++j)
                wn[j] = *(const float4*)(wb + (size_t)j * D + kn);
            const float4 h = Hs[buf][q][lane];
            #pragma unroll
            for (int j = 0; j < EPW; ++j) {
                acc[j] += h.x * wc[j].x;
                acc[j] += h.y * wc[j].y;
                acc[j] += h.z * wc[j].z;
                acc[j] += h.w * wc[j].w;
            }
            #pragma unroll
            for (int j = 0; j < EPW; ++j) wc[j] = wn[j];
        }
        __syncthreads();   // drains vmcnt -> next buffer ready; prev buffer reusable
    }

    // ---- gather logits in LDS: Ls[expert][token] ----
    #pragma unroll
    for (int j = 0; j < EPW; ++j) Ls[w * EPW + j][lane] = acc[j];
    __syncthreads();

    // ---- epilogue: one lane per token, online softmax + branchless top-2 ----
    if (tid < TPB) {
        const int tok = tid;
        float m = -INFINITY, Z = 0.f;
        float v1 = -INFINITY, v2 = -INFINITY;
        int   i1 = 0, i2 = 0;
        for (int e = 0; e < NE; ++e) {
            const float v = Ls[e][tok] + bias[e] + rbias[batch * NE + e];
            const float nm = fmaxf(m, v);
            Z = Z * __expf(m - nm) + __expf(v - nm);
            m = nm;
            const bool g1 = v > v1;
            const bool g2 = v > v2;
            const float nv2 = g1 ? v1 : (g2 ? v : v2);
            const int   ni2 = g1 ? i1 : (g2 ? e : i2);
            v1 = g1 ? v : v1;
            i1 = g1 ? e : i1;
            v2 = nv2;
            i2 = ni2;
        }
        const float p1 = __expf(v1 - m) / Z;
        const float p2 = __expf(v2 - m) / Z;
        const float s  = p1 + p2 + 1e-8f;
        const int gt = gt0 + tok;
        out[gt * 2 + 0] = p1 / s;
        out[gt * 2 + 1] = p2 / s;
        float* outI = out + 4 * 4096 * 2;
        outI[gt * 2 + 0] = (float)i1;
        outI[gt * 2 + 1] = (float)i2;
    }
}

extern "C" void kernel_launch(void* const* d_in, const int* in_sizes, int n_in,
                              void* d_out, int out_size, void* d_ws, size_t ws_size,
                              hipStream_t stream) {
    (void)in_sizes; (void)n_in; (void)d_ws; (void)ws_size; (void)out_size;
    const float* hidden = (const float*)d_in[0];
    const float* rbias  = (const float*)d_in[1];
    const float* W      = (const float*)d_in[2];
    const float* bias   = (const float*)d_in[3];
    float* out = (float*)d_out;

    const int n_tokens = 4 * 4096;
    dim3 grid(n_tokens / TPB);   // 256 blocks, 1 per CU
    dim3 block(512);             // 8 waves: 8 experts each, 2 waves/SIMD
    hipLaunchKernelGGL(router_kernel, grid, block, 0, stream,
                       hidden, rbias, W, bias, out);
}

// Round 4
// 461.486 us; speedup vs baseline: 1.6278x; 1.6278x over previous
//
#include <hip/hip_runtime.h>
#include <hip/hip_bf16.h>
#include <stdint.h>

// ExpertRouter via 6-term split-bf16 MFMA (h,w each split 3-way into bf16).
// logits = H @ W^T + b + rbias; softmax; top-2; renorm.
// H fp32 [16384,4096], W fp32 [64,4096].
// h = h1+h2+h3 (exact to 2^-26), w = w1+w2+w3 (prepass, exact to 2^-26).
// Keep terms h1w1 | h1w2,h2w1,h2w2,h1w3,h3w1 (hi-acc | lo-acc); dropped
// h2w3+h3w2 ~ 4e-8 RMS. K split 4-ways -> 32-add f32 chains (~2e-7 accum).
// Geometry: 256 blocks x 512 thr (8 waves). Wave (th,kq) = 32 tokens (2
// MFMA tiles) x K-quarter. A-frags straight from HBM (no LDS in main loop);
// W planes (1.5 MB bf16, d_ws) stay L2-resident; T=2 token-tiling keeps W
// L2 traffic ~768 MB (hidden under the 268 MB / 43 us HBM stream).

#define D    4096
#define NE   64
#define TOKB 64            // tokens per block
#define KQ   1024          // K per wave (quarter)
#define NIT  (KQ / 32)     // 32 k-steps

typedef __attribute__((ext_vector_type(8))) short bf16x8;
typedef __attribute__((ext_vector_type(4))) float f32x4;

__device__ __forceinline__ short f2bf(float x) {
    __hip_bfloat16 h = __float2bfloat16(x);   // RNE
    return *reinterpret_cast<short*>(&h);
}
__device__ __forceinline__ float bf2f(short s) {
    unsigned int u = ((unsigned int)(unsigned short)s) << 16;
    return __uint_as_float(u);
}
__device__ __forceinline__ void split3(float x, short& s1, short& s2, short& s3) {
    short a = f2bf(x);  float r1 = x - bf2f(a);
    short b = f2bf(r1); float r2 = r1 - bf2f(b);
    s1 = a; s2 = b; s3 = f2bf(r2);
}

// ---- pre-pass: W fp32 -> 3 bf16 planes (1.5 MB in d_ws) ----
__global__ void wsplit3_kernel(const float* __restrict__ W,
                               short* __restrict__ W1, short* __restrict__ W2,
                               short* __restrict__ W3) {
    const int n = NE * D;
    for (int i = blockIdx.x * blockDim.x + threadIdx.x; i < n;
         i += gridDim.x * blockDim.x) {
        short a, b, c;
        split3(W[i], a, b, c);
        W1[i] = a; W2[i] = b; W3[i] = c;
    }
}

template<bool WPRE>
__global__ __launch_bounds__(512)
void router_mfma6(const float* __restrict__ hidden,
                  const float* __restrict__ rbias,
                  const float* __restrict__ W,
                  const float* __restrict__ bias,
                  const short* __restrict__ W1,
                  const short* __restrict__ W2,
                  const short* __restrict__ W3,
                  float* __restrict__ out)
{
    __shared__ float Lp[2][TOKB][NE + 2];   // 33792 B partial-logit planes

    const int tid  = threadIdx.x;
    const int lane = tid & 63;
    const int w    = tid >> 6;
    const int kq   = w >> 1;          // K-quarter 0..3
    const int th   = w & 1;           // token half (32 tokens)
    const int tokbase = blockIdx.x * TOKB;
    const int batch   = tokbase >> 12;     // 4096 tokens per batch, 64 | 4096

    // m97-validated fragment conventions (16x16x32 bf16):
    // A feed: row = lane&15, k0 = (lane>>4)*8 ; B feed: same from W rows.
    // C/D:   col = lane&15, row = (lane>>4)*4 + reg.
    const int r16 = lane & 15;
    const int kg  = (lane >> 4) * 8;

    const float* hA[2];
    hA[0] = hidden + (size_t)(tokbase + th * 32 + r16) * D + kq * KQ + kg;
    hA[1] = hA[0] + (size_t)16 * D;

    const short* w1p[4]; const short* w2p[4]; const short* w3p[4];
    const float* wfp[4];
    #pragma unroll
    for (int t = 0; t < 4; ++t) {
        const size_t off = (size_t)(16 * t + r16) * D + kq * KQ + kg;
        if (WPRE) { w1p[t] = W1 + off; w2p[t] = W2 + off; w3p[t] = W3 + off; }
        else      { wfp[t] = W + off; }
    }

    f32x4 aH[2][4], aL[2][4];
    #pragma unroll
    for (int tt = 0; tt < 2; ++tt)
        #pragma unroll
        for (int t = 0; t < 4; ++t) {
            aH[tt][t] = (f32x4){0.f, 0.f, 0.f, 0.f};
            aL[tt][t] = (f32x4){0.f, 0.f, 0.f, 0.f};
        }

    for (int it = 0; it < NIT; ++it) {
        bf16x8 h1[2], h2[2], h3[2];
        #pragma unroll
        for (int tt = 0; tt < 2; ++tt) {
            const float4 a0 = *(const float4*)(hA[tt]);
            const float4 a1 = *(const float4*)(hA[tt] + 4);
            hA[tt] += 32;
            const float av[8] = {a0.x, a0.y, a0.z, a0.w, a1.x, a1.y, a1.z, a1.w};
            #pragma unroll
            for (int e = 0; e < 8; ++e) {
                short s1, s2, s3;
                split3(av[e], s1, s2, s3);
                h1[tt][e] = s1; h2[tt][e] = s2; h3[tt][e] = s3;
            }
        }
        #pragma unroll
        for (int t = 0; t < 4; ++t) {
            bf16x8 x1, x2, x3;
            if constexpr (WPRE) {
                x1 = *(const bf16x8*)(w1p[t]);
                x2 = *(const bf16x8*)(w2p[t]);
                x3 = *(const bf16x8*)(w3p[t]);
                w1p[t] += 32; w2p[t] += 32; w3p[t] += 32;
            } else {
                const float4 b0 = *(const float4*)(wfp[t]);
                const float4 b1 = *(const float4*)(wfp[t] + 4);
                wfp[t] += 32;
                const float bv[8] = {b0.x, b0.y, b0.z, b0.w, b1.x, b1.y, b1.z, b1.w};
                #pragma unroll
                for (int e = 0; e < 8; ++e) {
                    short s1, s2, s3;
                    split3(bv[e], s1, s2, s3);
                    x1[e] = s1; x2[e] = s2; x3[e] = s3;
                }
            }
            #pragma unroll
            for (int tt = 0; tt < 2; ++tt) {
                aH[tt][t] = __builtin_amdgcn_mfma_f32_16x16x32_bf16(h1[tt], x1, aH[tt][t], 0, 0, 0);
                aL[tt][t] = __builtin_amdgcn_mfma_f32_16x16x32_bf16(h1[tt], x2, aL[tt][t], 0, 0, 0);
                aL[tt][t] = __builtin_amdgcn_mfma_f32_16x16x32_bf16(h2[tt], x1, aL[tt][t], 0, 0, 0);
                aL[tt][t] = __builtin_amdgcn_mfma_f32_16x16x32_bf16(h2[tt], x2, aL[tt][t], 0, 0, 0);
                aL[tt][t] = __builtin_amdgcn_mfma_f32_16x16x32_bf16(h1[tt], x3, aL[tt][t], 0, 0, 0);
                aL[tt][t] = __builtin_amdgcn_mfma_f32_16x16x32_bf16(h3[tt], x1, aL[tt][t], 0, 0, 0);
            }
        }
    }

    // ---- K-quarter reduction: kq<2 store plane kq; kq>=2 add into plane kq-2 ----
    const int trow  = (lane >> 4) * 4;
    const int plane = kq & 1;
    float vals[2][4][4];
    #pragma unroll
    for (int tt = 0; tt < 2; ++tt)
        #pragma unroll
        for (int t = 0; t < 4; ++t)
            #pragma unroll
            for (int r = 0; r < 4; ++r)
                vals[tt][t][r] = aH[tt][t][r] + aL[tt][t][r];

    if (kq < 2) {
        #pragma unroll
        for (int tt = 0; tt < 2; ++tt)
            #pragma unroll
            for (int t = 0; t < 4; ++t)
                #pragma unroll
                for (int r = 0; r < 4; ++r)
                    Lp[plane][th * 32 + tt * 16 + trow + r][t * 16 + r16] = vals[tt][t][r];
    }
    __syncthreads();
    if (kq >= 2) {
        #pragma unroll
        for (int tt = 0; tt < 2; ++tt)
            #pragma unroll
            for (int t = 0; t < 4; ++t)
                #pragma unroll
                for (int r = 0; r < 4; ++r)
                    Lp[plane][th * 32 + tt * 16 + trow + r][t * 16 + r16] += vals[tt][t][r];
    }
    __syncthreads();

    // ---- epilogue: one lane per token, online softmax + branchless top-2 ----
    if (tid < TOKB) {
        const int tok = tid;
        float m = -INFINITY, Z = 0.f;
        float v1 = -INFINITY, v2 = -INFINITY;
        int   i1 = 0, i2 = 0;
        for (int e = 0; e < NE; ++e) {
            const float dot = Lp[0][tok][e] + Lp[1][tok][e];
            const float v = (dot + bias[e]) + rbias[batch * NE + e];  // ref association
            const float nm = fmaxf(m, v);
            Z = Z * __expf(m - nm) + __expf(v - nm);
            m = nm;
            const bool g1 = v > v1;
            const bool g2 = v > v2;
            const float nv2 = g1 ? v1 : (g2 ? v : v2);
            const int   ni2 = g1 ? i1 : (g2 ? e : i2);
            v1 = g1 ? v : v1;
            i1 = g1 ? e : i1;
            v2 = nv2;
            i2 = ni2;
        }
        const float p1 = __expf(v1 - m) / Z;
        const float p2 = __expf(v2 - m) / Z;
        const float s  = p1 + p2 + 1e-8f;
        const int gt = tokbase + tok;
        out[gt * 2 + 0] = p1 / s;
        out[gt * 2 + 1] = p2 / s;
        float* outI = out + 4 * 4096 * 2;
        outI[gt * 2 + 0] = (float)i1;
        outI[gt * 2 + 1] = (float)i2;
    }
}

extern "C" void kernel_launch(void* const* d_in, const int* in_sizes, int n_in,
                              void* d_out, int out_size, void* d_ws, size_t ws_size,
                              hipStream_t stream) {
    (void)in_sizes; (void)n_in; (void)out_size;
    const float* hidden = (const float*)d_in[0];
    const float* rbias  = (const float*)d_in[1];
    const float* W      = (const float*)d_in[2];
    const float* bias   = (const float*)d_in[3];
    float* out = (float*)d_out;

    const size_t wbytes = (size_t)3 * NE * D * sizeof(short);   // 1.5 MB
    const bool wpre = (ws_size >= wbytes) && (d_ws != nullptr);
    short* W1 = (short*)d_ws;
    short* W2 = W1 + (size_t)NE * D;
    short* W3 = W2 + (size_t)NE * D;

    const int n_tokens = 4 * 4096;
    dim3 grid(n_tokens / TOKB);   // 256 blocks, 1 per CU
    dim3 block(512);              // 8 waves: (token-half) x (K-quarter)

    if (wpre) {
        hipLaunchKernelGGL(wsplit3_kernel, dim3(512), dim3(256), 0, stream, W, W1, W2, W3);
        hipLaunchKernelGGL((router_mfma6<true>), grid, block, 0, stream,
                           hidden, rbias, W, bias, W1, W2, W3, out);
    } else {
        hipLaunchKernelGGL((router_mfma6<false>), grid, block, 0, stream,
                           hidden, rbias, W, bias,
                           (const short*)nullptr, (const short*)nullptr,
                           (const short*)nullptr, out);
    }
}

// Round 7
// 456.176 us; speedup vs baseline: 1.6468x; 1.0116x over previous
//
#include <hip/hip_runtime.h>
#include <hip/hip_bf16.h>
#include <stdint.h>

// ExpertRouter via 6-term split-bf16 MFMA (validated numerics from R4).
// R5: fragment-contiguous W layout (prepass) + explicit 2-phase register
// double-buffering of H and W + 2 independent blocks/CU.
// Geometry: grid 512 x 256 thr (4 waves). Block = 32 tokens; wave = K-quarter.
// Wave: 2 token-tiles x 4 expert-tiles x NIT=32 k-steps of 32.

#define D       4096
#define NE      64
#define TOKB    32
#define KQ      1024
#define NIT     (KQ / 32)      // 32
#define WSTRIDE 6144           // shorts per k-step in Wf: 3 planes * 4 tiles * 64 lanes * 8

typedef __attribute__((ext_vector_type(8))) short bf16x8;
typedef __attribute__((ext_vector_type(4))) float f32x4;

__device__ __forceinline__ short f2bf(float x) {
    __hip_bfloat16 h = __float2bfloat16(x);   // RNE
    return *reinterpret_cast<short*>(&h);
}
__device__ __forceinline__ float bf2f(short s) {
    unsigned int u = ((unsigned int)(unsigned short)s) << 16;
    return __uint_as_float(u);
}
__device__ __forceinline__ void split3(float x, short& a, short& b, short& c) {
    a = f2bf(x);  float r  = x - bf2f(a);
    b = f2bf(r);  float r2 = r - bf2f(b);
    c = f2bf(r2);
}

// ---- pre-pass: W fp32 -> 3 bf16 planes, stored in MFMA B-fragment order ----
// chunk (s,p,t,l) at short offset (((s*3+p)*4+t)*64+l)*8 holds
// plane_p of W[16t+(l&15)][s*32+(l>>4)*8 + 0..7]
__global__ void wfrag_kernel(const float* __restrict__ W, short* __restrict__ Wf) {
    const int idx = blockIdx.x * blockDim.x + threadIdx.x;
    if (idx >= 128 * 4 * 64) return;
    const int l = idx & 63, t = (idx >> 6) & 3, s = idx >> 8;
    const int e  = 16 * t + (l & 15);
    const int kb = s * 32 + ((l >> 4) * 8);
    bf16x8 c1, c2, c3;
    #pragma unroll
    for (int j = 0; j < 8; ++j) {
        short a, b, c;
        split3(W[(size_t)e * D + kb + j], a, b, c);
        c1[j] = a; c2[j] = b; c3[j] = c;
    }
    *(bf16x8*)(Wf + ((size_t)((s * 3 + 0) * 4 + t) * 64 + l) * 8) = c1;
    *(bf16x8*)(Wf + ((size_t)((s * 3 + 1) * 4 + t) * 64 + l) * 8) = c2;
    *(bf16x8*)(Wf + ((size_t)((s * 3 + 2) * 4 + t) * 64 + l) * 8) = c3;
}

template<bool WPRE>
__global__ __launch_bounds__(256, 2)
void router5(const float* __restrict__ hidden,
             const float* __restrict__ rbias,
             const float* __restrict__ W,
             const float* __restrict__ bias,
             const short* __restrict__ Wf,
             float* __restrict__ out)
{
    __shared__ float Lp[2][TOKB][NE + 2];

    const int tid  = threadIdx.x;
    const int lane = tid & 63;
    const int kq   = tid >> 6;                 // K-quarter 0..3
    const int tokbase = blockIdx.x * TOKB;
    const int batch   = tokbase >> 12;

    const int r16 = lane & 15;
    const int kg  = (lane >> 4) * 8;

    const float* h0 = hidden + (size_t)(tokbase + r16) * D + kq * KQ + kg;
    const float* h1 = h0 + (size_t)16 * D;
    const short* wv = Wf + (size_t)kq * NIT * WSTRIDE + lane * 8;
    const float* wf0 = W + (size_t)r16 * D + kq * KQ + kg;   // fallback path

    f32x4 aH[2][4], aL[2][4];
    #pragma unroll
    for (int tt = 0; tt < 2; ++tt)
        #pragma unroll
        for (int t = 0; t < 4; ++t) {
            aH[tt][t] = (f32x4){0.f, 0.f, 0.f, 0.f};
            aL[tt][t] = (f32x4){0.f, 0.f, 0.f, 0.f};
        }

    bf16x8 WA[12], WB[12];
    float4 HA[4], HB[4];

    #define LOADH(HH, IT) do { \
        const int itc = (IT) < NIT ? (IT) : NIT - 1; \
        const float* p0 = h0 + itc * 32; \
        const float* p1 = h1 + itc * 32; \
        HH[0] = *(const float4*)p0; HH[1] = *(const float4*)(p0 + 4); \
        HH[2] = *(const float4*)p1; HH[3] = *(const float4*)(p1 + 4); } while (0)

    #define LOADW(WW, IT) do { \
        const int itc = (IT) < NIT ? (IT) : NIT - 1; \
        const short* wp = wv + (size_t)itc * WSTRIDE; \
        _Pragma("unroll") \
        for (int j = 0; j < 12; ++j) WW[j] = *(const bf16x8*)(wp + j * 512); } while (0)

    #define COMPUTE(WW, HH, IT) do { \
        bf16x8 b1[2], b2[2], b3[2]; \
        _Pragma("unroll") \
        for (int tt = 0; tt < 2; ++tt) { \
            const float4 a0 = HH[tt * 2], a1 = HH[tt * 2 + 1]; \
            const float av[8] = {a0.x, a0.y, a0.z, a0.w, a1.x, a1.y, a1.z, a1.w}; \
            _Pragma("unroll") \
            for (int e2 = 0; e2 < 8; ++e2) { \
                short sa, sb, sc; split3(av[e2], sa, sb, sc); \
                b1[tt][e2] = sa; b2[tt][e2] = sb; b3[tt][e2] = sc; } } \
        _Pragma("unroll") \
        for (int t = 0; t < 4; ++t) { \
            bf16x8 x1, x2, x3; \
            if constexpr (WPRE) { x1 = WW[0 * 4 + t]; x2 = WW[1 * 4 + t]; x3 = WW[2 * 4 + t]; } \
            else { \
                const float* wp = wf0 + (size_t)t * 16 * D + (IT) * 32; \
                const float4 q0 = *(const float4*)wp, q1 = *(const float4*)(wp + 4); \
                const float bv[8] = {q0.x, q0.y, q0.z, q0.w, q1.x, q1.y, q1.z, q1.w}; \
                _Pragma("unroll") \
                for (int e2 = 0; e2 < 8; ++e2) { \
                    short sa, sb, sc; split3(bv[e2], sa, sb, sc); \
                    x1[e2] = sa; x2[e2] = sb; x3[e2] = sc; } } \
            _Pragma("unroll") \
            for (int tt = 0; tt < 2; ++tt) { \
                aH[tt][t] = __builtin_amdgcn_mfma_f32_16x16x32_bf16(b1[tt], x1, aH[tt][t], 0, 0, 0); \
                aL[tt][t] = __builtin_amdgcn_mfma_f32_16x16x32_bf16(b1[tt], x2, aL[tt][t], 0, 0, 0); \
                aL[tt][t] = __builtin_amdgcn_mfma_f32_16x16x32_bf16(b2[tt], x1, aL[tt][t], 0, 0, 0); \
                aL[tt][t] = __builtin_amdgcn_mfma_f32_16x16x32_bf16(b2[tt], x2, aL[tt][t], 0, 0, 0); \
                aL[tt][t] = __builtin_amdgcn_mfma_f32_16x16x32_bf16(b1[tt], x3, aL[tt][t], 0, 0, 0); \
                aL[tt][t] = __builtin_amdgcn_mfma_f32_16x16x32_bf16(b3[tt], x1, aL[tt][t], 0, 0, 0); } } } while (0)

    // ---- software-pipelined main loop (2-phase, 1-iter load lookahead) ----
    if constexpr (WPRE) LOADW(WA, 0);
    LOADH(HA, 0);
    for (int it = 0; it < NIT; it += 2) {
        if constexpr (WPRE) LOADW(WB, it + 1);
        LOADH(HB, it + 1);
        COMPUTE(WA, HA, it);
        if constexpr (WPRE) LOADW(WA, it + 2);
        LOADH(HA, it + 2);
        COMPUTE(WB, HB, it + 1);
    }

    // ---- K-quarter reduction: kq<2 store plane kq; kq>=2 add into plane kq-2 ----
    const int trow  = (lane >> 4) * 4;
    const int plane = kq & 1;
    float vals[2][4][4];
    #pragma unroll
    for (int tt = 0; tt < 2; ++tt)
        #pragma unroll
        for (int t = 0; t < 4; ++t)
            #pragma unroll
            for (int r = 0; r < 4; ++r)
                vals[tt][t][r] = aH[tt][t][r] + aL[tt][t][r];

    if (kq < 2) {
        #pragma unroll
        for (int tt = 0; tt < 2; ++tt)
            #pragma unroll
            for (int t = 0; t < 4; ++t)
                #pragma unroll
                for (int r = 0; r < 4; ++r)
                    Lp[plane][tt * 16 + trow + r][t * 16 + r16] = vals[tt][t][r];
    }
    __syncthreads();
    if (kq >= 2) {
        #pragma unroll
        for (int tt = 0; tt < 2; ++tt)
            #pragma unroll
            for (int t = 0; t < 4; ++t)
                #pragma unroll
                for (int r = 0; r < 4; ++r)
                    Lp[plane][tt * 16 + trow + r][t * 16 + r16] += vals[tt][t][r];
    }
    __syncthreads();

    // ---- epilogue: one lane per token, online softmax + branchless top-2 ----
    if (tid < TOKB) {
        const int tok = tid;
        float m = -INFINITY, Z = 0.f;
        float v1 = -INFINITY, v2 = -INFINITY;
        int   i1 = 0, i2 = 0;
        for (int e = 0; e < NE; ++e) {
            const float dot = Lp[0][tok][e] + Lp[1][tok][e];
            const float v = (dot + bias[e]) + rbias[batch * NE + e];  // ref association
            const float nm = fmaxf(m, v);
            Z = Z * __expf(m - nm) + __expf(v - nm);
            m = nm;
            const bool g1 = v > v1;
            const bool g2 = v > v2;
            const float nv2 = g1 ? v1 : (g2 ? v : v2);
            const int   ni2 = g1 ? i1 : (g2 ? e : i2);
            v1 = g1 ? v : v1;
            i1 = g1 ? e : i1;
            v2 = nv2;
            i2 = ni2;
        }
        const float p1 = __expf(v1 - m) / Z;
        const float p2 = __expf(v2 - m) / Z;
        const float s  = p1 + p2 + 1e-8f;
        const int gt = tokbase + tok;
        out[gt * 2 + 0] = p1 / s;
        out[gt * 2 + 1] = p2 / s;
        float* outI = out + 4 * 4096 * 2;
        outI[gt * 2 + 0] = (float)i1;
        outI[gt * 2 + 1] = (float)i2;
    }
    #undef LOADH
    #undef LOADW
    #undef COMPUTE
}

extern "C" void kernel_launch(void* const* d_in, const int* in_sizes, int n_in,
                              void* d_out, int out_size, void* d_ws, size_t ws_size,
                              hipStream_t stream) {
    (void)in_sizes; (void)n_in; (void)out_size;
    const float* hidden = (const float*)d_in[0];
    const float* rbias  = (const float*)d_in[1];
    const float* W      = (const float*)d_in[2];
    const float* bias   = (const float*)d_in[3];
    float* out = (float*)d_out;

    const size_t wbytes = (size_t)3 * NE * D * sizeof(short);   // 1.5 MB
    const bool wpre = (ws_size >= wbytes) && (d_ws != nullptr);
    short* Wf = (short*)d_ws;

    const int n_tokens = 4 * 4096;
    dim3 grid(n_tokens / TOKB);   // 512 blocks -> 2 blocks/CU
    dim3 block(256);              // 4 waves: K-quarters

    if (wpre) {
        hipLaunchKernelGGL(wfrag_kernel, dim3(128), dim3(256), 0, stream, W, Wf);
        hipLaunchKernelGGL((router5<true>), grid, block, 0, stream,
                           hidden, rbias, W, bias, Wf, out);
    } else {
        hipLaunchKernelGGL((router5<false>), grid, block, 0, stream,
                           hidden, rbias, W, bias, (const short*)nullptr, out);
    }
}

// Round 9
// 406.287 us; speedup vs baseline: 1.8490x; 1.1228x over previous
//
#include <hip/hip_runtime.h>
#include <hip/hip_bf16.h>
#include <stdint.h>

// ExpertRouter, R8: m97-style global_load_lds staging + 1 barrier per K-chunk.
// logits = H @ W^T + b + rbias; softmax; top-2; renorm.
// H fp32 [16384,4096]; W pre-split into 3 bf16 planes in MFMA B-fragment order
// (Wf, d_ws, 1.5 MB, L2-resident). 6-term split-bf16 MFMA (R4-validated).
// Block = 64 tokens x 64 experts x K/KSPLIT. Wave = 32 tok x 32 exp.
// K-split partials -> d_ws; wave-per-token reduce+softmax+top2 epilogue kernel.

#define D     4096
#define NE    64
#define NTOK  16384
#define TOKB  64
#define BK    32

typedef __attribute__((ext_vector_type(8))) short bf16x8;
typedef __attribute__((ext_vector_type(4))) float f32x4;
typedef const __attribute__((address_space(1))) unsigned int* gp_t;
typedef __attribute__((address_space(3))) unsigned int* lp_t;

__device__ __forceinline__ short f2bf(float x) {
    __hip_bfloat16 h = __float2bfloat16(x);   // RNE
    return *reinterpret_cast<short*>(&h);
}
__device__ __forceinline__ float bf2f(short s) {
    unsigned int u = ((unsigned int)(unsigned short)s) << 16;
    return __uint_as_float(u);
}
__device__ __forceinline__ void split3(float x, short& a, short& b, short& c) {
    a = f2bf(x);  float r  = x - bf2f(a);
    b = f2bf(r);  float r2 = r - bf2f(b);
    c = f2bf(r2);
}

// ---- pre-pass: W fp32 -> 3 bf16 planes in MFMA B-fragment order ----
// chunk (s,p,t,l) at short offset (((s*3+p)*4+t)*64+l)*8 holds
// plane_p of W[16t+(l&15)][s*32+(l>>4)*8 + 0..7]   (s = global k-step 0..127)
__global__ void wfrag_kernel(const float* __restrict__ W, short* __restrict__ Wf) {
    const int idx = blockIdx.x * blockDim.x + threadIdx.x;
    if (idx >= 128 * 4 * 64) return;
    const int l = idx & 63, t = (idx >> 6) & 3, s = idx >> 8;
    const int e  = 16 * t + (l & 15);
    const int kb = s * 32 + ((l >> 4) * 8);
    bf16x8 c1, c2, c3;
    #pragma unroll
    for (int j = 0; j < 8; ++j) {
        short a, b, c;
        split3(W[(size_t)e * D + kb + j], a, b, c);
        c1[j] = a; c2[j] = b; c3[j] = c;
    }
    *(bf16x8*)(Wf + ((size_t)((s * 3 + 0) * 4 + t) * 64 + l) * 8) = c1;
    *(bf16x8*)(Wf + ((size_t)((s * 3 + 1) * 4 + t) * 64 + l) * 8) = c2;
    *(bf16x8*)(Wf + ((size_t)((s * 3 + 2) * 4 + t) * 64 + l) * 8) = c3;
}

// ---- main GEMM: partial logits for one K-slice of 64 tokens ----
template<int KSPLIT>
__global__ __launch_bounds__(256, 4)
void router8(const float* __restrict__ hidden,
             const short* __restrict__ Wf,
             float* __restrict__ part)
{
    constexpr int KQ = D / KSPLIT;
    constexpr int NCHUNK = KQ / BK;

    __shared__ float Hs[2][TOKB * BK];     // 16 KB, row-major [tok][k], XOR-swizzled cols
    __shared__ short Ws[2][12 * 512];      // 24 KB, 12 frags x (64 lanes x 8 bf16)

    const int tid  = threadIdx.x;
    const int lane = tid & 63;
    const int w    = tid >> 6;
    const int tokblk = blockIdx.x & 255;
    const int q      = blockIdx.x >> 8;    // K-slice index
    const int tok0   = tokblk * TOKB;
    const int k0     = q * KQ;

    // staging precompute (wave-uniform instr ids, per-lane addresses)
    const int w5   = w * 5;                               // instrs [w5, w5+5)
    const int hrow = lane >> 3;                           // row within 8-row group
    const int hcol = ((lane & 7) ^ hrow) * 4;             // swizzled source col (floats)
    const float* hbase = hidden + (size_t)tok0 * D + k0;
    const int sbase = q * NCHUNK;

    #define STAGE(BUF, C) do { \
        const int c_ = (C); \
        _Pragma("unroll") \
        for (int ii = 0; ii < 5; ++ii) { \
            const int i = w5 + ii; \
            if (i < 8) { \
                const float* src = hbase + (size_t)(i * 8 + hrow) * D + c_ * BK + hcol; \
                __builtin_amdgcn_global_load_lds((gp_t)(const void*)src, \
                    (lp_t)(void*)&Hs[BUF][i * 8 * BK], 16, 0, 0); \
            } else { \
                const short* src = Wf + ((size_t)(sbase + c_) * 12 + (i - 8)) * 512 + lane * 8; \
                __builtin_amdgcn_global_load_lds((gp_t)(const void*)src, \
                    (lp_t)(void*)&Ws[BUF][(i - 8) * 512], 16, 0, 0); \
            } \
        } \
    } while (0)

    // compute-role indices
    const int wt  = w >> 1;     // token half (32 tokens)
    const int we  = w & 1;      // expert half (32 experts)
    const int r16 = lane & 15;
    const int qtr = lane >> 4;

    f32x4 aH[2][2], aL[2][2];
    #pragma unroll
    for (int tt = 0; tt < 2; ++tt)
        #pragma unroll
        for (int tp = 0; tp < 2; ++tp) {
            aH[tt][tp] = (f32x4){0.f, 0.f, 0.f, 0.f};
            aL[tt][tp] = (f32x4){0.f, 0.f, 0.f, 0.f};
        }

    STAGE(0, 0);
    __syncthreads();

    for (int c = 0; c < NCHUNK; ++c) {
        const int buf = c & 1;
        if (c + 1 < NCHUNK) STAGE(buf ^ 1, c + 1);

        // A fragments: H[tok][kg..kg+7], swizzled ds reads (2-way max conflicts)
        bf16x8 a1[2], a2[2], a3[2];
        #pragma unroll
        for (int tt = 0; tt < 2; ++tt) {
            const int row = wt * 32 + tt * 16 + r16;
            const int sw  = row & 7;
            const int g0  = qtr * 2;
            const float4 fa = *(const float4*)&Hs[buf][row * BK + ((g0 ^ sw) << 2)];
            const float4 fb = *(const float4*)&Hs[buf][row * BK + (((g0 + 1) ^ sw) << 2)];
            const float av[8] = {fa.x, fa.y, fa.z, fa.w, fb.x, fb.y, fb.z, fb.w};
            #pragma unroll
            for (int e = 0; e < 8; ++e) {
                short sa, sb, sc;
                split3(av[e], sa, sb, sc);
                a1[tt][e] = sa; a2[tt][e] = sb; a3[tt][e] = sc;
            }
        }
        // B fragments (linear, conflict-free) + 6-term MFMA
        #pragma unroll
        for (int tp = 0; tp < 2; ++tp) {
            const int tile = we * 2 + tp;
            const bf16x8 x1 = *(const bf16x8*)&Ws[buf][(0 * 4 + tile) * 512 + lane * 8];
            const bf16x8 x2 = *(const bf16x8*)&Ws[buf][(1 * 4 + tile) * 512 + lane * 8];
            const bf16x8 x3 = *(const bf16x8*)&Ws[buf][(2 * 4 + tile) * 512 + lane * 8];
            #pragma unroll
            for (int tt = 0; tt < 2; ++tt) {
                aH[tt][tp] = __builtin_amdgcn_mfma_f32_16x16x32_bf16(a1[tt], x1, aH[tt][tp], 0, 0, 0);
                aL[tt][tp] = __builtin_amdgcn_mfma_f32_16x16x32_bf16(a1[tt], x2, aL[tt][tp], 0, 0, 0);
                aL[tt][tp] = __builtin_amdgcn_mfma_f32_16x16x32_bf16(a2[tt], x1, aL[tt][tp], 0, 0, 0);
                aL[tt][tp] = __builtin_amdgcn_mfma_f32_16x16x32_bf16(a2[tt], x2, aL[tt][tp], 0, 0, 0);
                aL[tt][tp] = __builtin_amdgcn_mfma_f32_16x16x32_bf16(a1[tt], x3, aL[tt][tp], 0, 0, 0);
                aL[tt][tp] = __builtin_amdgcn_mfma_f32_16x16x32_bf16(a3[tt], x1, aL[tt][tp], 0, 0, 0);
            }
        }
        __syncthreads();   // drains staged DMA (vmcnt) + LDS reads before buffer reuse
    }

    // ---- store partial logits: C/D layout col=lane&15, row=(lane>>4)*4+r ----
    const int trow = qtr * 4;
    #pragma unroll
    for (int tt = 0; tt < 2; ++tt)
        #pragma unroll
        for (int tp = 0; tp < 2; ++tp)
            #pragma unroll
            for (int r = 0; r < 4; ++r) {
                const int gtok = tok0 + wt * 32 + tt * 16 + trow + r;
                const int gexp = we * 32 + tp * 16 + r16;
                part[((size_t)q * NTOK + gtok) * NE + gexp] = aH[tt][tp][r] + aL[tt][tp][r];
            }
    #undef STAGE
}

// ---- epilogue: one wave per token, lane = expert; reduce + softmax + top2 ----
__global__ __launch_bounds__(256)
void reduce_topk(const float* __restrict__ part,
                 const float* __restrict__ rbias,
                 const float* __restrict__ bias,
                 float* __restrict__ out, int ksplit)
{
    const int tid  = threadIdx.x;
    const int lane = tid & 63;
    const int tok  = blockIdx.x * 4 + (tid >> 6);

    float s = 0.f;
    for (int p = 0; p < ksplit; ++p)
        s += part[((size_t)p * NTOK + tok) * NE + lane];
    const int batch = tok >> 12;
    const float v = (s + bias[lane]) + rbias[batch * NE + lane];   // ref association

    float m = v;
    #pragma unroll
    for (int off = 32; off >= 1; off >>= 1)
        m = fmaxf(m, __shfl_xor(m, off, 64));
    float Z = __expf(v - m);
    #pragma unroll
    for (int off = 32; off >= 1; off >>= 1)
        Z += __shfl_xor(Z, off, 64);

    float v1 = v, v2 = -INFINITY;
    int   i1 = lane, i2 = 0;
    #pragma unroll
    for (int off = 1; off <= 32; off <<= 1) {
        const float V1 = __shfl_xor(v1, off, 64);
        const int   I1 = __shfl_xor(i1, off, 64);
        const float V2 = __shfl_xor(v2, off, 64);
        const int   I2 = __shfl_xor(i2, off, 64);
        const bool a = V1 > v1;
        const float w1 = a ? V1 : v1;  const int j1 = a ? I1 : i1;
        const float lo = a ? v1 : V1;  const int lj = a ? i1 : I1;
        const float c2 = a ? V2 : v2;  const int j2 = a ? I2 : i2;
        const bool b2 = c2 > lo;
        v1 = w1; i1 = j1;
        v2 = b2 ? c2 : lo;
        i2 = b2 ? j2 : lj;
    }
    if (lane == 0) {
        const float p1 = __expf(v1 - m) / Z;
        const float p2 = __expf(v2 - m) / Z;
        const float sm = p1 + p2 + 1e-8f;
        out[tok * 2 + 0] = p1 / sm;
        out[tok * 2 + 1] = p2 / sm;
        float* outI = out + NTOK * 2;
        outI[tok * 2 + 0] = (float)i1;
        outI[tok * 2 + 1] = (float)i2;
    }
}

extern "C" void kernel_launch(void* const* d_in, const int* in_sizes, int n_in,
                              void* d_out, int out_size, void* d_ws, size_t ws_size,
                              hipStream_t stream) {
    (void)in_sizes; (void)n_in; (void)out_size;
    const float* hidden = (const float*)d_in[0];
    const float* rbias  = (const float*)d_in[1];
    const float* W      = (const float*)d_in[2];
    const float* bias   = (const float*)d_in[3];
    float* out = (float*)d_out;

    short* Wf   = (short*)d_ws;                              // 1.5 MB
    float* part = (float*)((char*)d_ws + (2u << 20));        // KSPLIT * 4 MB
    const size_t plane = (size_t)NTOK * NE * sizeof(float);  // 4 MB

    int ksplit = 1;
    if (ws_size >= (2u << 20) + 4 * plane)      ksplit = 4;
    else if (ws_size >= (2u << 20) + 2 * plane) ksplit = 2;

    hipLaunchKernelGGL(wfrag_kernel, dim3(128), dim3(256), 0, stream, W, Wf);
    if (ksplit == 4)
        hipLaunchKernelGGL((router8<4>), dim3(256 * 4), dim3(256), 0, stream, hidden, Wf, part);
    else if (ksplit == 2)
        hipLaunchKernelGGL((router8<2>), dim3(256 * 2), dim3(256), 0, stream, hidden, Wf, part);
    else
        hipLaunchKernelGGL((router8<1>), dim3(256), dim3(256), 0, stream, hidden, Wf, part);
    hipLaunchKernelGGL(reduce_topk, dim3(NTOK / 4), dim3(256), 0, stream,
                       part, rbias, bias, out, ksplit);
}